// Round 9
// baseline (298.455 us; speedup 1.0000x reference)
//
#include <hip/hip_runtime.h>
#include <cstdint>
#include <cstddef>

#define S_LEN 4096
#define DMODEL 1024
#define NHEADS 16
#define HDK 64
#define DKV 256
#define NTOT 1536  // 1024 Q + 256 K + 256 V packed N
// SCALE * log2(e), folded into Q projection epilogue so softmax is exp2(s)
#define QSCALE 0.18033688011112042f

typedef __bf16 bf16;
typedef __bf16 bf16x8 __attribute__((ext_vector_type(8)));
typedef float f32x4 __attribute__((ext_vector_type(4)));

typedef __attribute__((address_space(3))) void lds_void;
typedef const __attribute__((address_space(1))) void gbl_void;

// async global->LDS, 16B/lane, dest = wave-uniform base + lane*16
__device__ __forceinline__ void gload16(const void* g, void* l) {
  __builtin_amdgcn_global_load_lds((gbl_void*)g, (lds_void*)l, 16, 0, 0);
}

// ---------------- fused prep: weight transposes + x downconvert + mask ----------------
__global__ __launch_bounds__(256) void prep(
    const float* __restrict__ x, const int* __restrict__ mask,
    const float* __restrict__ Wq, const float* __restrict__ Wk,
    const float* __restrict__ Wv, const float* __restrict__ Wo,
    bf16* __restrict__ xb, float* __restrict__ mkf, bf16* __restrict__ mkb,
    bf16* __restrict__ Wqt, bf16* __restrict__ Wkt,
    bf16* __restrict__ Wvt, bf16* __restrict__ Wot) {
  const int z = blockIdx.z;
  if (z < 4) {
    const float* src;
    bf16* dst;
    int C;
    switch (z) {
      case 0: src = Wq; dst = Wqt; C = DMODEL; break;
      case 1: src = Wk; dst = Wkt; C = DKV; break;
      case 2: src = Wv; dst = Wvt; C = DKV; break;
      default: src = Wo; dst = Wot; C = DMODEL; break;
    }
    const int c0 = blockIdx.x * 32;
    if (c0 >= C) return;
    __shared__ float tile[32][33];
    const int tx = threadIdx.x & 31;
    const int ty = threadIdx.x >> 5;
    const int r0 = blockIdx.y * 32;
#pragma unroll
    for (int i = 0; i < 4; i++)
      tile[ty + i * 8][tx] = src[(size_t)(r0 + ty + i * 8) * C + c0 + tx];
    __syncthreads();
#pragma unroll
    for (int i = 0; i < 4; i++)
      dst[(size_t)(c0 + ty + i * 8) * DMODEL + r0 + tx] = (bf16)tile[tx][ty + i * 8];
  } else {
    const int b = blockIdx.y * 32 + blockIdx.x;           // 0..1023
    const int half = z - 4;                               // 0 or 1
    const int i = ((half * 1024 + b) * 256 + (int)threadIdx.x) * 8;
    float4 a = *(const float4*)(x + i);
    float4 c = *(const float4*)(x + i + 4);
    bf16 o[8] = {(bf16)a.x, (bf16)a.y, (bf16)a.z, (bf16)a.w,
                 (bf16)c.x, (bf16)c.y, (bf16)c.z, (bf16)c.w};
    *(uint4*)(xb + i) = *(uint4*)o;
    if (half == 1 && b < 2) {
      const int mi = (b * 256 + (int)threadIdx.x) * 8;
#pragma unroll
      for (int j = 0; j < 8; j++) {
        float keep = mask[mi + j] ? 0.0f : 1.0f;
        mkf[mi + j] = keep;
        mkb[mi + j] = (bf16)keep;
      }
    }
  }
}

// ---------------- GEMM core: 64x128 tile, BK=64, global_load_lds, XOR swizzle ----------------
// grid (N/128, M/64). 4 waves 2x2; wave tile 32(M) x 64(N) -> acc[2][4].
// LDS rows 128B = 8 chunks of 16B; chunk c holds global chunk c ^ (row&7).
// QKV=1: A=x, Bt=packed[1536][1024] -> Q(*QSCALE)/K/Vt(transposed,*mkf)
// QKV=0: O-projection, fp32 out with bias bo.
template <int QKV>
__global__ __launch_bounds__(256) void gemm_ld(
    const bf16* __restrict__ A, const bf16* __restrict__ Bt, int M, int N, int K,
    const float* __restrict__ bq, const float* __restrict__ bk,
    const float* __restrict__ bv, const float* __restrict__ mkf,
    bf16* __restrict__ Qb, bf16* __restrict__ Kb, bf16* __restrict__ Vtb,
    const float* __restrict__ bo, float* __restrict__ Co) {
  __shared__ bf16 As[64 * 64];
  __shared__ bf16 Bs[128 * 64];
  const int t = threadIdx.x;
  const int lane = t & 63;
  const int wave = t >> 6;
  const int m0 = blockIdx.y * 64;
  const int n0 = blockIdx.x * 128;
  const int wm = (wave >> 1) * 32;
  const int wn = (wave & 1) * 64;
  const int lr = lane & 15;
  const int quad = lane >> 4;

  const int sr = lane >> 3;                                // 0..7
  const int sc = ((lane & 7) ^ (lane >> 3)) * 8;           // bf16 offset in 64-K slab

  f32x4 acc[2][4] = {};

  for (int k0 = 0; k0 < K; k0 += 64) {
    __syncthreads();
#pragma unroll
    for (int j = 0; j < 2; j++) {
      const int rbase = wave * 16 + j * 8;
      gload16(A + (size_t)(m0 + rbase + sr) * K + k0 + sc, &As[rbase * 64]);
    }
#pragma unroll
    for (int j = 0; j < 4; j++) {
      const int rbase = wave * 32 + j * 8;
      gload16(Bt + (size_t)(n0 + rbase + sr) * K + k0 + sc, &Bs[rbase * 64]);
    }
    __syncthreads();
#pragma unroll
    for (int kh2 = 0; kh2 < 2; kh2++) {
      const int fo = ((kh2 * 4 + quad) ^ (lr & 7)) * 8;  // swizzled chunk offset
      bf16x8 af[2], bfr[4];
#pragma unroll
      for (int mt = 0; mt < 2; mt++)
        af[mt] = *(const bf16x8*)(&As[(wm + mt * 16 + lr) * 64 + fo]);
#pragma unroll
      for (int nt = 0; nt < 4; nt++)
        bfr[nt] = *(const bf16x8*)(&Bs[(wn + nt * 16 + lr) * 64 + fo]);
#pragma unroll
      for (int mt = 0; mt < 2; mt++)
#pragma unroll
        for (int nt = 0; nt < 4; nt++)
          acc[mt][nt] = __builtin_amdgcn_mfma_f32_16x16x32_bf16(af[mt], bfr[nt], acc[mt][nt], 0, 0, 0);
    }
  }

#pragma unroll
  for (int nt = 0; nt < 4; nt++) {
    const int n = n0 + wn + nt * 16 + lr;
    if (QKV) {
      if (n < DMODEL) {
        const float b = bq[n];
#pragma unroll
        for (int mt = 0; mt < 2; mt++)
#pragma unroll
          for (int r = 0; r < 4; r++) {
            const int m = m0 + wm + mt * 16 + quad * 4 + r;
            Qb[(size_t)m * DMODEL + n] = (bf16)((acc[mt][nt][r] + b) * QSCALE);
          }
      } else if (n < DMODEL + DKV) {
        const float b = bk[n - DMODEL];
#pragma unroll
        for (int mt = 0; mt < 2; mt++)
#pragma unroll
          for (int r = 0; r < 4; r++) {
            const int m = m0 + wm + mt * 16 + quad * 4 + r;
            Kb[(size_t)m * DKV + (n - DMODEL)] = (bf16)(acc[mt][nt][r] + b);
          }
      } else {
        const float b = bv[n - DMODEL - DKV];
#pragma unroll
        for (int mt = 0; mt < 2; mt++)
#pragma unroll
          for (int r = 0; r < 4; r++) {
            const int m = m0 + wm + mt * 16 + quad * 4 + r;
            Vtb[(size_t)(n - DMODEL - DKV) * S_LEN + m] = (bf16)((acc[mt][nt][r] + b) * mkf[m]);
          }
      }
    } else {
      const float b = bo[n];
#pragma unroll
      for (int mt = 0; mt < 2; mt++)
#pragma unroll
        for (int r = 0; r < 4; r++) {
          const int m = m0 + wm + mt * 16 + quad * 4 + r;
          Co[(size_t)m * N + n] = acc[mt][nt][r] + b;
        }
    }
  }
}

// ---------------- flash attention: R5 structure + register-prefetch pipeline ----------------
// grid: (S/128, H). 4 waves; wave w owns q-rows [q0+32w, q0+32w+32).
// Tile i+1's K/V/mask are loaded into VGPRs during tile i's compute phase,
// then stored regs->LDS after the loop-top barrier: global latency overlaps compute.
__global__ __launch_bounds__(256) void flash_attn(
    const bf16* __restrict__ Q, const bf16* __restrict__ K,
    const bf16* __restrict__ Vt, const bf16* __restrict__ mkb,
    bf16* __restrict__ O) {
  const int h = blockIdx.y;
  const int kvh = h >> 2;
  const int q0 = blockIdx.x * 128;
  const int t = threadIdx.x;
  const int lane = t & 63;
  const int wave = t >> 6;
  const int lr = lane & 15;
  const int quad = lane >> 4;

  __shared__ bf16 Ks[128][72];     // [key][dk]
  __shared__ bf16 Vs[64][136];     // [dk][key]
  __shared__ bf16 Ps[4][32][36];   // per-wave P [qrow][key-chunk of 32]
  __shared__ bf16 mks[128];

  bf16x8 aq[2][2];
#pragma unroll
  for (int qt = 0; qt < 2; qt++) {
    const int qrow = q0 + wave * 32 + qt * 16 + lr;
    aq[qt][0] = *(const bf16x8*)(Q + (size_t)qrow * DMODEL + h * HDK + quad * 8);
    aq[qt][1] = *(const bf16x8*)(Q + (size_t)qrow * DMODEL + h * HDK + 32 + quad * 8);
  }

  // staging address components (per thread, fixed)
  const bf16* Kbase = K + kvh * HDK;
  const bf16* Vbase = Vt + (size_t)kvh * HDK * S_LEN;
  int rowK[4], chK[4], rowV[4], chV[4];
#pragma unroll
  for (int i = 0; i < 4; i++) {
    const int id = t + i * 256;
    rowK[i] = id >> 3;  chK[i] = (id & 7) * 8;
    rowV[i] = id >> 4;  chV[i] = (id & 15) * 8;
  }

  uint4 rK[4], rV[4], rM;
  // preload tile 0
#pragma unroll
  for (int i = 0; i < 4; i++) {
    rK[i] = *(const uint4*)(Kbase + (size_t)rowK[i] * DKV + chK[i]);
    rV[i] = *(const uint4*)(Vbase + (size_t)rowV[i] * S_LEN + chV[i]);
  }
  if (t < 16) rM = *(const uint4*)(mkb + t * 8);

  f32x4 o_acc[2][4] = {};
  f32x4 l_acc[2] = {};

  for (int kv0 = 0; kv0 < S_LEN; kv0 += 128) {
    __syncthreads();  // previous tile's LDS reads complete
#pragma unroll
    for (int i = 0; i < 4; i++) {
      *(uint4*)(&Ks[rowK[i]][chK[i]]) = rK[i];
      *(uint4*)(&Vs[rowV[i]][chV[i]]) = rV[i];
    }
    if (t < 16) *(uint4*)(&mks[t * 8]) = rM;
    __syncthreads();  // staging visible

    // prefetch tile i+1 (latency overlaps the compute below)
    const int kvn = kv0 + 128;
    if (kvn < S_LEN) {
#pragma unroll
      for (int i = 0; i < 4; i++) {
        rK[i] = *(const uint4*)(Kbase + (size_t)(kvn + rowK[i]) * DKV + chK[i]);
        rV[i] = *(const uint4*)(Vbase + (size_t)rowV[i] * S_LEN + kvn + chV[i]);
      }
      if (t < 16) rM = *(const uint4*)(mkb + kvn + t * 8);
    }

#pragma unroll
    for (int kc = 0; kc < 4; kc++) {
      bf16x8 ak[2][2];
#pragma unroll
      for (int ntl = 0; ntl < 2; ntl++) {
        const int krow = kc * 32 + ntl * 16 + lr;
        ak[ntl][0] = *(const bf16x8*)(&Ks[krow][quad * 8]);
        ak[ntl][1] = *(const bf16x8*)(&Ks[krow][32 + quad * 8]);
      }
      // S^T = K @ Q^T : C-layout col=qrow(lane&15), row=key(quad*4+r)
#pragma unroll
      for (int qt = 0; qt < 2; qt++) {
#pragma unroll
        for (int ntl = 0; ntl < 2; ntl++) {
          f32x4 s = {};
          s = __builtin_amdgcn_mfma_f32_16x16x32_bf16(ak[ntl][0], aq[qt][0], s, 0, 0, 0);
          s = __builtin_amdgcn_mfma_f32_16x16x32_bf16(ak[ntl][1], aq[qt][1], s, 0, 0, 0);
          bf16 p4[4];
#pragma unroll
          for (int r = 0; r < 4; r++) p4[r] = (bf16)__builtin_amdgcn_exp2f(s[r]);
          *(uint2*)(&Ps[wave][qt * 16 + lr][ntl * 16 + quad * 4]) = *(uint2*)p4;
        }
      }
      // V and mask fragments hoisted: shared across both qt tiles
      bf16x8 bvf[4];
#pragma unroll
      for (int ntv = 0; ntv < 4; ntv++)
        bvf[ntv] = *(const bf16x8*)(&Vs[ntv * 16 + lr][kc * 32 + quad * 8]);
      bf16x8 mkfv = *(const bf16x8*)(&mks[kc * 32 + quad * 8]);
#pragma unroll
      for (int qt = 0; qt < 2; qt++) {
        bf16x8 ap = *(const bf16x8*)(&Ps[wave][qt * 16 + lr][quad * 8]);
#pragma unroll
        for (int ntv = 0; ntv < 4; ntv++)
          o_acc[qt][ntv] = __builtin_amdgcn_mfma_f32_16x16x32_bf16(ap, bvf[ntv], o_acc[qt][ntv], 0, 0, 0);
        l_acc[qt] = __builtin_amdgcn_mfma_f32_16x16x32_bf16(ap, mkfv, l_acc[qt], 0, 0, 0);
      }
    }
  }

#pragma unroll
  for (int qt = 0; qt < 2; qt++) {
#pragma unroll
    for (int ntv = 0; ntv < 4; ntv++) {
#pragma unroll
      for (int r = 0; r < 4; r++) {
        const int row = q0 + wave * 32 + qt * 16 + quad * 4 + r;
        O[(size_t)row * DMODEL + h * HDK + ntv * 16 + lr] =
            (bf16)(o_acc[qt][ntv][r] / l_acc[qt][r]);
      }
    }
  }
}

// ---------------- launch ----------------
extern "C" void kernel_launch(void* const* d_in, const int* in_sizes, int n_in,
                              void* d_out, int out_size, void* d_ws, size_t ws_size,
                              hipStream_t stream) {
  const float* x = (const float*)d_in[0];
  const int* mask = (const int*)d_in[1];
  const float* Wq = (const float*)d_in[2];
  const float* bq = (const float*)d_in[3];
  const float* Wk = (const float*)d_in[4];
  const float* bk = (const float*)d_in[5];
  const float* Wv = (const float*)d_in[6];
  const float* bv = (const float*)d_in[7];
  const float* Wo = (const float*)d_in[8];
  const float* bo = (const float*)d_in[9];
  float* out = (float*)d_out;

  char* w = (char*)d_ws;
  bf16* xb  = (bf16*)w; w += (size_t)S_LEN * DMODEL * 2;
  bf16* Wqt = (bf16*)w; w += (size_t)DMODEL * DMODEL * 2;  // packed B rows 0..1023
  bf16* Wkt = (bf16*)w; w += (size_t)DKV * DMODEL * 2;     // rows 1024..1279
  bf16* Wvt = (bf16*)w; w += (size_t)DKV * DMODEL * 2;     // rows 1280..1535
  bf16* Wot = (bf16*)w; w += (size_t)DMODEL * DMODEL * 2;
  bf16* Qb  = (bf16*)w; w += (size_t)S_LEN * DMODEL * 2;
  bf16* Kb  = (bf16*)w; w += (size_t)S_LEN * DKV * 2;
  bf16* Vtb = (bf16*)w; w += (size_t)DKV * S_LEN * 2;
  bf16* Ob  = (bf16*)w; w += (size_t)S_LEN * DMODEL * 2;
  float* mkf = (float*)w; w += (size_t)S_LEN * 4;
  bf16* mkb = (bf16*)w; w += (size_t)S_LEN * 2;

  // fused prep (1 dispatch): transposes + x convert + mask
  prep<<<dim3(32, 32, 6), 256, 0, stream>>>(
      x, mask, Wq, Wk, Wv, Wo, xb, mkf, mkb, Wqt, Wkt, Wvt, Wot);

  // fused QKV projection (packed N = 1536), 64-row M tiles -> 768 blocks
  gemm_ld<1><<<dim3(NTOT / 128, S_LEN / 64), 256, 0, stream>>>(
      xb, Wqt, S_LEN, NTOT, DMODEL, bq, bk, bv, mkf, Qb, Kb, Vtb, nullptr, nullptr);

  // attention
  flash_attn<<<dim3(S_LEN / 128, NHEADS), 256, 0, stream>>>(Qb, Kb, Vtb, mkb, Ob);

  // output projection (fp32 out), 64-row M tiles -> 512 blocks
  gemm_ld<0><<<dim3(DMODEL / 128, S_LEN / 64), 256, 0, stream>>>(
      Ob, Wot, S_LEN, DMODEL, DMODEL, nullptr, nullptr, nullptr, nullptr,
      nullptr, nullptr, nullptr, bo, out);
}

// Round 10
// 224.215 us; speedup vs baseline: 1.3311x; 1.3311x over previous
//
#include <hip/hip_runtime.h>
#include <cstdint>
#include <cstddef>

#define S_LEN 4096
#define DMODEL 1024
#define NHEADS 16
#define HDK 64
#define DKV 256
#define NTOT 1536  // 1024 Q + 256 K + 256 V packed N
// SCALE * log2(e), folded into Q projection epilogue so softmax is exp2(s)
#define QSCALE 0.18033688011112042f

typedef __bf16 bf16;
typedef __bf16 bf16x8 __attribute__((ext_vector_type(8)));
typedef float f32x4 __attribute__((ext_vector_type(4)));

typedef __attribute__((address_space(3))) void lds_void;
typedef const __attribute__((address_space(1))) void gbl_void;

// async global->LDS, 16B/lane, dest = wave-uniform base + lane*16
__device__ __forceinline__ void gload16(const void* g, void* l) {
  __builtin_amdgcn_global_load_lds((gbl_void*)g, (lds_void*)l, 16, 0, 0);
}

// ---------------- fused prep: weight transposes + x downconvert + mask ----------------
__global__ __launch_bounds__(256) void prep(
    const float* __restrict__ x, const int* __restrict__ mask,
    const float* __restrict__ Wq, const float* __restrict__ Wk,
    const float* __restrict__ Wv, const float* __restrict__ Wo,
    bf16* __restrict__ xb, float* __restrict__ mkf, bf16* __restrict__ mkb,
    bf16* __restrict__ Wqt, bf16* __restrict__ Wkt,
    bf16* __restrict__ Wvt, bf16* __restrict__ Wot) {
  const int z = blockIdx.z;
  if (z < 4) {
    const float* src;
    bf16* dst;
    int C;
    switch (z) {
      case 0: src = Wq; dst = Wqt; C = DMODEL; break;
      case 1: src = Wk; dst = Wkt; C = DKV; break;
      case 2: src = Wv; dst = Wvt; C = DKV; break;
      default: src = Wo; dst = Wot; C = DMODEL; break;
    }
    const int c0 = blockIdx.x * 32;
    if (c0 >= C) return;
    __shared__ float tile[32][33];
    const int tx = threadIdx.x & 31;
    const int ty = threadIdx.x >> 5;
    const int r0 = blockIdx.y * 32;
#pragma unroll
    for (int i = 0; i < 4; i++)
      tile[ty + i * 8][tx] = src[(size_t)(r0 + ty + i * 8) * C + c0 + tx];
    __syncthreads();
#pragma unroll
    for (int i = 0; i < 4; i++)
      dst[(size_t)(c0 + ty + i * 8) * DMODEL + r0 + tx] = (bf16)tile[tx][ty + i * 8];
  } else {
    const int b = blockIdx.y * 32 + blockIdx.x;           // 0..1023
    const int half = z - 4;                               // 0 or 1
    const int i = ((half * 1024 + b) * 256 + (int)threadIdx.x) * 8;
    float4 a = *(const float4*)(x + i);
    float4 c = *(const float4*)(x + i + 4);
    bf16 o[8] = {(bf16)a.x, (bf16)a.y, (bf16)a.z, (bf16)a.w,
                 (bf16)c.x, (bf16)c.y, (bf16)c.z, (bf16)c.w};
    *(uint4*)(xb + i) = *(uint4*)o;
    if (half == 1 && b < 2) {
      const int mi = (b * 256 + (int)threadIdx.x) * 8;
#pragma unroll
      for (int j = 0; j < 8; j++) {
        float keep = mask[mi + j] ? 0.0f : 1.0f;
        mkf[mi + j] = keep;
        mkb[mi + j] = (bf16)keep;
      }
    }
  }
}

// ---------------- GEMM core: 64x128 tile, BK=64, global_load_lds, XOR swizzle ----------------
// (R9-validated: non-flash 123 -> 107 us) grid (N/128, M/64). 4 waves 2x2.
template <int QKV>
__global__ __launch_bounds__(256) void gemm_ld(
    const bf16* __restrict__ A, const bf16* __restrict__ Bt, int M, int N, int K,
    const float* __restrict__ bq, const float* __restrict__ bk,
    const float* __restrict__ bv, const float* __restrict__ mkf,
    bf16* __restrict__ Qb, bf16* __restrict__ Kb, bf16* __restrict__ Vtb,
    const float* __restrict__ bo, float* __restrict__ Co) {
  __shared__ bf16 As[64 * 64];
  __shared__ bf16 Bs[128 * 64];
  const int t = threadIdx.x;
  const int lane = t & 63;
  const int wave = t >> 6;
  const int m0 = blockIdx.y * 64;
  const int n0 = blockIdx.x * 128;
  const int wm = (wave >> 1) * 32;
  const int wn = (wave & 1) * 64;
  const int lr = lane & 15;
  const int quad = lane >> 4;

  const int sr = lane >> 3;                                // 0..7
  const int sc = ((lane & 7) ^ (lane >> 3)) * 8;           // bf16 offset in 64-K slab

  f32x4 acc[2][4] = {};

  for (int k0 = 0; k0 < K; k0 += 64) {
    __syncthreads();
#pragma unroll
    for (int j = 0; j < 2; j++) {
      const int rbase = wave * 16 + j * 8;
      gload16(A + (size_t)(m0 + rbase + sr) * K + k0 + sc, &As[rbase * 64]);
    }
#pragma unroll
    for (int j = 0; j < 4; j++) {
      const int rbase = wave * 32 + j * 8;
      gload16(Bt + (size_t)(n0 + rbase + sr) * K + k0 + sc, &Bs[rbase * 64]);
    }
    __syncthreads();
#pragma unroll
    for (int kh2 = 0; kh2 < 2; kh2++) {
      const int fo = ((kh2 * 4 + quad) ^ (lr & 7)) * 8;  // swizzled chunk offset
      bf16x8 af[2], bfr[4];
#pragma unroll
      for (int mt = 0; mt < 2; mt++)
        af[mt] = *(const bf16x8*)(&As[(wm + mt * 16 + lr) * 64 + fo]);
#pragma unroll
      for (int nt = 0; nt < 4; nt++)
        bfr[nt] = *(const bf16x8*)(&Bs[(wn + nt * 16 + lr) * 64 + fo]);
#pragma unroll
      for (int mt = 0; mt < 2; mt++)
#pragma unroll
        for (int nt = 0; nt < 4; nt++)
          acc[mt][nt] = __builtin_amdgcn_mfma_f32_16x16x32_bf16(af[mt], bfr[nt], acc[mt][nt], 0, 0, 0);
    }
  }

#pragma unroll
  for (int nt = 0; nt < 4; nt++) {
    const int n = n0 + wn + nt * 16 + lr;
    if (QKV) {
      if (n < DMODEL) {
        const float b = bq[n];
#pragma unroll
        for (int mt = 0; mt < 2; mt++)
#pragma unroll
          for (int r = 0; r < 4; r++) {
            const int m = m0 + wm + mt * 16 + quad * 4 + r;
            Qb[(size_t)m * DMODEL + n] = (bf16)((acc[mt][nt][r] + b) * QSCALE);
          }
      } else if (n < DMODEL + DKV) {
        const float b = bk[n - DMODEL];
#pragma unroll
        for (int mt = 0; mt < 2; mt++)
#pragma unroll
          for (int r = 0; r < 4; r++) {
            const int m = m0 + wm + mt * 16 + quad * 4 + r;
            Kb[(size_t)m * DKV + (n - DMODEL)] = (bf16)(acc[mt][nt][r] + b);
          }
      } else {
        const float b = bv[n - DMODEL - DKV];
#pragma unroll
        for (int mt = 0; mt < 2; mt++)
#pragma unroll
          for (int r = 0; r < 4; r++) {
            const int m = m0 + wm + mt * 16 + quad * 4 + r;
            Vtb[(size_t)(n - DMODEL - DKV) * S_LEN + m] = (bf16)((acc[mt][nt][r] + b) * mkf[m]);
          }
      }
    } else {
      const float b = bo[n];
#pragma unroll
      for (int mt = 0; mt < 2; mt++)
#pragma unroll
        for (int r = 0; r < 4; r++) {
          const int m = m0 + wm + mt * 16 + quad * 4 + r;
          Co[(size_t)m * N + n] = acc[mt][nt][r] + b;
        }
    }
  }
}

// ---------------- flash attention: async-DMA double-buffered K/V, 1 barrier/iter ----------------
// grid: (S/128, H). 4 waves; wave w owns q-rows [q0+32w, q0+32w+32).
// Loop: barrier (drains tile i's global_load_lds via compiler vmcnt(0)) ->
// issue tile i+1 DMA into buf^1 -> compute tile i. DMA latency overlaps compute;
// no VGPRs held (R9's register-prefetch spilled to scratch: WRITE_SIZE 8->206 MB).
// K LDS: [128][64] unpadded, chunk c holds global chunk c^(row&7).
// V LDS: [64][128] unpadded, chunk c holds global chunk c^(row&15).
// Mask fragments read per-wave directly from global (8 KB, L1-resident).
__global__ __launch_bounds__(256) void flash_attn(
    const bf16* __restrict__ Q, const bf16* __restrict__ K,
    const bf16* __restrict__ Vt, const bf16* __restrict__ mkb,
    bf16* __restrict__ O) {
  const int h = blockIdx.y;
  const int kvh = h >> 2;
  const int q0 = blockIdx.x * 128;
  const int t = threadIdx.x;
  const int lane = t & 63;
  const int wave = t >> 6;
  const int lr = lane & 15;
  const int quad = lane >> 4;

  __shared__ bf16 Ks[2][128 * 64];   // 32 KB
  __shared__ bf16 Vs[2][64 * 128];   // 32 KB
  __shared__ bf16 Ps[4][32][36];     // 9 KB, per-wave private round-trip

  bf16x8 aq[2][2];
#pragma unroll
  for (int qt = 0; qt < 2; qt++) {
    const int qrow = q0 + wave * 32 + qt * 16 + lr;
    aq[qt][0] = *(const bf16x8*)(Q + (size_t)qrow * DMODEL + h * HDK + quad * 8);
    aq[qt][1] = *(const bf16x8*)(Q + (size_t)qrow * DMODEL + h * HDK + 32 + quad * 8);
  }

  const bf16* Kg = K + kvh * HDK;
  const bf16* Vg = Vt + (size_t)kvh * HDK * S_LEN;
  // K staging: lane -> row lane>>3 (of 8), global chunk (lane&7)^(lane>>3)
  const int krl = lane >> 3;
  const int kgc = ((lane & 7) ^ (lane >> 3)) * 8;
  // V staging: lane -> row lane>>4 (of 4), global chunk (lane&15)^((rb+row)&15)
  const int vrl = lane >> 4;

  // prologue: stage tile 0 into buf 0
#pragma unroll
  for (int j = 0; j < 4; j++) {
    const int rb = wave * 32 + j * 8;
    gload16(Kg + (size_t)(rb + krl) * DKV + kgc, &Ks[0][rb * 64]);
  }
#pragma unroll
  for (int j = 0; j < 4; j++) {
    const int rb = wave * 16 + j * 4;
    const int g = ((lane & 15) ^ (j * 4 + vrl)) * 8;
    gload16(Vg + (size_t)(rb + vrl) * S_LEN + g, &Vs[0][rb * 128]);
  }

  f32x4 o_acc[2][4] = {};
  f32x4 l_acc[2] = {};
  int buf = 0;

  for (int kv0 = 0; kv0 < S_LEN; kv0 += 128) {
    __syncthreads();  // drains this tile's DMA (vmcnt0 before s_barrier) + prev reads
    const int kvn = kv0 + 128;
    if (kvn < S_LEN) {
      const int nb = buf ^ 1;
#pragma unroll
      for (int j = 0; j < 4; j++) {
        const int rb = wave * 32 + j * 8;
        gload16(Kg + (size_t)(kvn + rb + krl) * DKV + kgc, &Ks[nb][rb * 64]);
      }
#pragma unroll
      for (int j = 0; j < 4; j++) {
        const int rb = wave * 16 + j * 4;
        const int g = ((lane & 15) ^ (j * 4 + vrl)) * 8;
        gload16(Vg + (size_t)(rb + vrl) * S_LEN + kvn + g, &Vs[nb][rb * 128]);
      }
    }
    const bf16* Ksb = Ks[buf];
    const bf16* Vsb = Vs[buf];

#pragma unroll
    for (int kc = 0; kc < 4; kc++) {
      bf16x8 ak[2][2];
#pragma unroll
      for (int ntl = 0; ntl < 2; ntl++) {
        const int krow = kc * 32 + ntl * 16 + lr;
        ak[ntl][0] = *(const bf16x8*)(&Ksb[krow * 64 + ((quad) ^ (lr & 7)) * 8]);
        ak[ntl][1] = *(const bf16x8*)(&Ksb[krow * 64 + ((4 + quad) ^ (lr & 7)) * 8]);
      }
      // S^T = K @ Q^T : C-layout col=qrow(lane&15), row=key(quad*4+r)
#pragma unroll
      for (int qt = 0; qt < 2; qt++) {
#pragma unroll
        for (int ntl = 0; ntl < 2; ntl++) {
          f32x4 s = {};
          s = __builtin_amdgcn_mfma_f32_16x16x32_bf16(ak[ntl][0], aq[qt][0], s, 0, 0, 0);
          s = __builtin_amdgcn_mfma_f32_16x16x32_bf16(ak[ntl][1], aq[qt][1], s, 0, 0, 0);
          bf16 p4[4];
#pragma unroll
          for (int r = 0; r < 4; r++) p4[r] = (bf16)__builtin_amdgcn_exp2f(s[r]);
          *(uint2*)(&Ps[wave][qt * 16 + lr][ntl * 16 + quad * 4]) = *(uint2*)p4;
        }
      }
      // V fragments (swizzled) + mask fragment from global (L1-hit)
      bf16x8 bvf[4];
#pragma unroll
      for (int ntv = 0; ntv < 4; ntv++) {
        const int vrow = ntv * 16 + lr;
        bvf[ntv] = *(const bf16x8*)(&Vsb[vrow * 128 + ((kc * 4 + quad) ^ lr) * 8]);
      }
      const bf16x8 mkfv = *(const bf16x8*)(mkb + kv0 + kc * 32 + quad * 8);
#pragma unroll
      for (int qt = 0; qt < 2; qt++) {
        bf16x8 ap = *(const bf16x8*)(&Ps[wave][qt * 16 + lr][quad * 8]);
#pragma unroll
        for (int ntv = 0; ntv < 4; ntv++)
          o_acc[qt][ntv] = __builtin_amdgcn_mfma_f32_16x16x32_bf16(ap, bvf[ntv], o_acc[qt][ntv], 0, 0, 0);
        l_acc[qt] = __builtin_amdgcn_mfma_f32_16x16x32_bf16(ap, mkfv, l_acc[qt], 0, 0, 0);
      }
    }
    buf ^= 1;
  }

#pragma unroll
  for (int qt = 0; qt < 2; qt++) {
#pragma unroll
    for (int ntv = 0; ntv < 4; ntv++) {
#pragma unroll
      for (int r = 0; r < 4; r++) {
        const int row = q0 + wave * 32 + qt * 16 + quad * 4 + r;
        O[(size_t)row * DMODEL + h * HDK + ntv * 16 + lr] =
            (bf16)(o_acc[qt][ntv][r] / l_acc[qt][r]);
      }
    }
  }
}

// ---------------- launch ----------------
extern "C" void kernel_launch(void* const* d_in, const int* in_sizes, int n_in,
                              void* d_out, int out_size, void* d_ws, size_t ws_size,
                              hipStream_t stream) {
  const float* x = (const float*)d_in[0];
  const int* mask = (const int*)d_in[1];
  const float* Wq = (const float*)d_in[2];
  const float* bq = (const float*)d_in[3];
  const float* Wk = (const float*)d_in[4];
  const float* bk = (const float*)d_in[5];
  const float* Wv = (const float*)d_in[6];
  const float* bv = (const float*)d_in[7];
  const float* Wo = (const float*)d_in[8];
  const float* bo = (const float*)d_in[9];
  float* out = (float*)d_out;

  char* w = (char*)d_ws;
  bf16* xb  = (bf16*)w; w += (size_t)S_LEN * DMODEL * 2;
  bf16* Wqt = (bf16*)w; w += (size_t)DMODEL * DMODEL * 2;  // packed B rows 0..1023
  bf16* Wkt = (bf16*)w; w += (size_t)DKV * DMODEL * 2;     // rows 1024..1279
  bf16* Wvt = (bf16*)w; w += (size_t)DKV * DMODEL * 2;     // rows 1280..1535
  bf16* Wot = (bf16*)w; w += (size_t)DMODEL * DMODEL * 2;
  bf16* Qb  = (bf16*)w; w += (size_t)S_LEN * DMODEL * 2;
  bf16* Kb  = (bf16*)w; w += (size_t)S_LEN * DKV * 2;
  bf16* Vtb = (bf16*)w; w += (size_t)DKV * S_LEN * 2;
  bf16* Ob  = (bf16*)w; w += (size_t)S_LEN * DMODEL * 2;
  float* mkf = (float*)w; w += (size_t)S_LEN * 4;
  bf16* mkb = (bf16*)w; w += (size_t)S_LEN * 2;

  // fused prep (1 dispatch): transposes + x convert + mask
  prep<<<dim3(32, 32, 6), 256, 0, stream>>>(
      x, mask, Wq, Wk, Wv, Wo, xb, mkf, mkb, Wqt, Wkt, Wvt, Wot);

  // fused QKV projection (packed N = 1536), 64-row M tiles -> 768 blocks
  gemm_ld<1><<<dim3(NTOT / 128, S_LEN / 64), 256, 0, stream>>>(
      xb, Wqt, S_LEN, NTOT, DMODEL, bq, bk, bv, mkf, Qb, Kb, Vtb, nullptr, nullptr);

  // attention
  flash_attn<<<dim3(S_LEN / 128, NHEADS), 256, 0, stream>>>(Qb, Kb, Vtb, mkb, Ob);

  // output projection (fp32 out), 64-row M tiles -> 512 blocks
  gemm_ld<0><<<dim3(DMODEL / 128, S_LEN / 64), 256, 0, stream>>>(
      Ob, Wot, S_LEN, DMODEL, DMODEL, nullptr, nullptr, nullptr, nullptr,
      nullptr, nullptr, nullptr, bo, out);
}

// Round 11
// 214.695 us; speedup vs baseline: 1.3901x; 1.0443x over previous
//
#include <hip/hip_runtime.h>
#include <cstdint>
#include <cstddef>

#define S_LEN 4096
#define DMODEL 1024
#define NHEADS 16
#define HDK 64
#define DKV 256
#define NTOT 1536  // 1024 Q + 256 K + 256 V packed N
// SCALE * log2(e), folded into Q projection epilogue so softmax is exp2(s)
#define QSCALE 0.18033688011112042f

typedef __bf16 bf16;
typedef __bf16 bf16x8 __attribute__((ext_vector_type(8)));
typedef float f32x4 __attribute__((ext_vector_type(4)));

typedef __attribute__((address_space(3))) void lds_void;
typedef const __attribute__((address_space(1))) void gbl_void;

// async global->LDS, 16B/lane, dest = wave-uniform base + lane*16
__device__ __forceinline__ void gload16(const void* g, void* l) {
  __builtin_amdgcn_global_load_lds((gbl_void*)g, (lds_void*)l, 16, 0, 0);
}

// ---------------- fused prep: weight transposes + x downconvert + mask ----------------
__global__ __launch_bounds__(256) void prep(
    const float* __restrict__ x, const int* __restrict__ mask,
    const float* __restrict__ Wq, const float* __restrict__ Wk,
    const float* __restrict__ Wv, const float* __restrict__ Wo,
    bf16* __restrict__ xb, float* __restrict__ mkf, bf16* __restrict__ mkb,
    bf16* __restrict__ Wqt, bf16* __restrict__ Wkt,
    bf16* __restrict__ Wvt, bf16* __restrict__ Wot) {
  const int z = blockIdx.z;
  if (z < 4) {
    const float* src;
    bf16* dst;
    int C;
    switch (z) {
      case 0: src = Wq; dst = Wqt; C = DMODEL; break;
      case 1: src = Wk; dst = Wkt; C = DKV; break;
      case 2: src = Wv; dst = Wvt; C = DKV; break;
      default: src = Wo; dst = Wot; C = DMODEL; break;
    }
    const int c0 = blockIdx.x * 32;
    if (c0 >= C) return;
    __shared__ float tile[32][33];
    const int tx = threadIdx.x & 31;
    const int ty = threadIdx.x >> 5;
    const int r0 = blockIdx.y * 32;
#pragma unroll
    for (int i = 0; i < 4; i++)
      tile[ty + i * 8][tx] = src[(size_t)(r0 + ty + i * 8) * C + c0 + tx];
    __syncthreads();
#pragma unroll
    for (int i = 0; i < 4; i++)
      dst[(size_t)(c0 + ty + i * 8) * DMODEL + r0 + tx] = (bf16)tile[tx][ty + i * 8];
  } else {
    const int b = blockIdx.y * 32 + blockIdx.x;           // 0..1023
    const int half = z - 4;                               // 0 or 1
    const int i = ((half * 1024 + b) * 256 + (int)threadIdx.x) * 8;
    float4 a = *(const float4*)(x + i);
    float4 c = *(const float4*)(x + i + 4);
    bf16 o[8] = {(bf16)a.x, (bf16)a.y, (bf16)a.z, (bf16)a.w,
                 (bf16)c.x, (bf16)c.y, (bf16)c.z, (bf16)c.w};
    *(uint4*)(xb + i) = *(uint4*)o;
    if (half == 1 && b < 2) {
      const int mi = (b * 256 + (int)threadIdx.x) * 8;
#pragma unroll
      for (int j = 0; j < 8; j++) {
        float keep = mask[mi + j] ? 0.0f : 1.0f;
        mkf[mi + j] = keep;
        mkb[mi + j] = (bf16)keep;
      }
    }
  }
}

// ---------------- GEMM: 64x128 tile, BK=64, async DMA, XCD-aware scheduling ----------------
// 1D grid (M/64)*(N/128) blocks. Dispatch maps bid -> XCD round-robin (bid&7);
// decode so XCD x owns m-stripe [x*8*64, x*8*64+512) and sweeps all n-tiles:
// A-stripe (1 MB) + full B (<=3 MB) stay resident in the 4 MB per-XCD L2,
// collapsing HBM refetch ~6x vs naive 2D order.
template <int QKV>
__global__ __launch_bounds__(256) void gemm_ld(
    const bf16* __restrict__ A, const bf16* __restrict__ Bt, int M, int N, int K,
    int NT,  // n-tile count = N/128
    const float* __restrict__ bq, const float* __restrict__ bk,
    const float* __restrict__ bv, const float* __restrict__ mkf,
    bf16* __restrict__ Qb, bf16* __restrict__ Kb, bf16* __restrict__ Vtb,
    const float* __restrict__ bo, float* __restrict__ Co) {
  __shared__ bf16 As[64 * 64];
  __shared__ bf16 Bs[128 * 64];
  const int t = threadIdx.x;
  const int lane = t & 63;
  const int wave = t >> 6;

  // XCD-aware decode: xcd = bid&7 (round-robin dispatch heuristic)
  const int bid = blockIdx.x;
  const int xcd = bid & 7;
  const int local = bid >> 3;
  const int m_local = local / NT;
  const int ntile = local - m_local * NT;
  const int mchunk = (M >> 6) >> 3;  // m-tiles per XCD
  const int m0 = (xcd * mchunk + m_local) * 64;
  const int n0 = ntile * 128;

  const int wm = (wave >> 1) * 32;
  const int wn = (wave & 1) * 64;
  const int lr = lane & 15;
  const int quad = lane >> 4;

  const int sr = lane >> 3;                                // 0..7
  const int sc = ((lane & 7) ^ (lane >> 3)) * 8;           // bf16 offset in 64-K slab

  f32x4 acc[2][4] = {};

  for (int k0 = 0; k0 < K; k0 += 64) {
    __syncthreads();
#pragma unroll
    for (int j = 0; j < 2; j++) {
      const int rbase = wave * 16 + j * 8;
      gload16(A + (size_t)(m0 + rbase + sr) * K + k0 + sc, &As[rbase * 64]);
    }
#pragma unroll
    for (int j = 0; j < 4; j++) {
      const int rbase = wave * 32 + j * 8;
      gload16(Bt + (size_t)(n0 + rbase + sr) * K + k0 + sc, &Bs[rbase * 64]);
    }
    __syncthreads();
#pragma unroll
    for (int kh2 = 0; kh2 < 2; kh2++) {
      const int fo = ((kh2 * 4 + quad) ^ (lr & 7)) * 8;  // swizzled chunk offset
      bf16x8 af[2], bfr[4];
#pragma unroll
      for (int mt = 0; mt < 2; mt++)
        af[mt] = *(const bf16x8*)(&As[(wm + mt * 16 + lr) * 64 + fo]);
#pragma unroll
      for (int nt = 0; nt < 4; nt++)
        bfr[nt] = *(const bf16x8*)(&Bs[(wn + nt * 16 + lr) * 64 + fo]);
#pragma unroll
      for (int mt = 0; mt < 2; mt++)
#pragma unroll
        for (int nt = 0; nt < 4; nt++)
          acc[mt][nt] = __builtin_amdgcn_mfma_f32_16x16x32_bf16(af[mt], bfr[nt], acc[mt][nt], 0, 0, 0);
    }
  }

#pragma unroll
  for (int nt = 0; nt < 4; nt++) {
    const int n = n0 + wn + nt * 16 + lr;
    if (QKV) {
      if (n < DMODEL) {
        const float b = bq[n];
#pragma unroll
        for (int mt = 0; mt < 2; mt++)
#pragma unroll
          for (int r = 0; r < 4; r++) {
            const int m = m0 + wm + mt * 16 + quad * 4 + r;
            Qb[(size_t)m * DMODEL + n] = (bf16)((acc[mt][nt][r] + b) * QSCALE);
          }
      } else if (n < DMODEL + DKV) {
        const float b = bk[n - DMODEL];
#pragma unroll
        for (int mt = 0; mt < 2; mt++)
#pragma unroll
          for (int r = 0; r < 4; r++) {
            const int m = m0 + wm + mt * 16 + quad * 4 + r;
            Kb[(size_t)m * DKV + (n - DMODEL)] = (bf16)(acc[mt][nt][r] + b);
          }
      } else {
        const float b = bv[n - DMODEL - DKV];
#pragma unroll
        for (int mt = 0; mt < 2; mt++)
#pragma unroll
          for (int r = 0; r < 4; r++) {
            const int m = m0 + wm + mt * 16 + quad * 4 + r;
            Vtb[(size_t)(n - DMODEL - DKV) * S_LEN + m] = (bf16)((acc[mt][nt][r] + b) * mkf[m]);
          }
      }
    } else {
      const float b = bo[n];
#pragma unroll
      for (int mt = 0; mt < 2; mt++)
#pragma unroll
        for (int r = 0; r < 4; r++) {
          const int m = m0 + wm + mt * 16 + quad * 4 + r;
          Co[(size_t)m * N + n] = acc[mt][nt][r] + b;
        }
    }
  }
}

// ---------------- flash attention: async-DMA double-buffered K/V, 1 barrier/iter ----------------
// (R10-validated: 101.6 us, 0 LDS conflicts, no spill.)
__global__ __launch_bounds__(256) void flash_attn(
    const bf16* __restrict__ Q, const bf16* __restrict__ K,
    const bf16* __restrict__ Vt, const bf16* __restrict__ mkb,
    bf16* __restrict__ O) {
  const int h = blockIdx.y;
  const int kvh = h >> 2;
  const int q0 = blockIdx.x * 128;
  const int t = threadIdx.x;
  const int lane = t & 63;
  const int wave = t >> 6;
  const int lr = lane & 15;
  const int quad = lane >> 4;

  __shared__ bf16 Ks[2][128 * 64];   // 32 KB
  __shared__ bf16 Vs[2][64 * 128];   // 32 KB
  __shared__ bf16 Ps[4][32][36];     // 9 KB, per-wave private round-trip

  bf16x8 aq[2][2];
#pragma unroll
  for (int qt = 0; qt < 2; qt++) {
    const int qrow = q0 + wave * 32 + qt * 16 + lr;
    aq[qt][0] = *(const bf16x8*)(Q + (size_t)qrow * DMODEL + h * HDK + quad * 8);
    aq[qt][1] = *(const bf16x8*)(Q + (size_t)qrow * DMODEL + h * HDK + 32 + quad * 8);
  }

  const bf16* Kg = K + kvh * HDK;
  const bf16* Vg = Vt + (size_t)kvh * HDK * S_LEN;
  const int krl = lane >> 3;
  const int kgc = ((lane & 7) ^ (lane >> 3)) * 8;
  const int vrl = lane >> 4;

  // prologue: stage tile 0 into buf 0
#pragma unroll
  for (int j = 0; j < 4; j++) {
    const int rb = wave * 32 + j * 8;
    gload16(Kg + (size_t)(rb + krl) * DKV + kgc, &Ks[0][rb * 64]);
  }
#pragma unroll
  for (int j = 0; j < 4; j++) {
    const int rb = wave * 16 + j * 4;
    const int g = ((lane & 15) ^ (j * 4 + vrl)) * 8;
    gload16(Vg + (size_t)(rb + vrl) * S_LEN + g, &Vs[0][rb * 128]);
  }

  f32x4 o_acc[2][4] = {};
  f32x4 l_acc[2] = {};
  int buf = 0;

  for (int kv0 = 0; kv0 < S_LEN; kv0 += 128) {
    __syncthreads();  // drains this tile's DMA + prev tile's LDS reads
    const int kvn = kv0 + 128;
    if (kvn < S_LEN) {
      const int nb = buf ^ 1;
#pragma unroll
      for (int j = 0; j < 4; j++) {
        const int rb = wave * 32 + j * 8;
        gload16(Kg + (size_t)(kvn + rb + krl) * DKV + kgc, &Ks[nb][rb * 64]);
      }
#pragma unroll
      for (int j = 0; j < 4; j++) {
        const int rb = wave * 16 + j * 4;
        const int g = ((lane & 15) ^ (j * 4 + vrl)) * 8;
        gload16(Vg + (size_t)(rb + vrl) * S_LEN + kvn + g, &Vs[nb][rb * 128]);
      }
    }
    const bf16* Ksb = Ks[buf];
    const bf16* Vsb = Vs[buf];

#pragma unroll
    for (int kc = 0; kc < 4; kc++) {
      bf16x8 ak[2][2];
#pragma unroll
      for (int ntl = 0; ntl < 2; ntl++) {
        const int krow = kc * 32 + ntl * 16 + lr;
        ak[ntl][0] = *(const bf16x8*)(&Ksb[krow * 64 + ((quad) ^ (lr & 7)) * 8]);
        ak[ntl][1] = *(const bf16x8*)(&Ksb[krow * 64 + ((4 + quad) ^ (lr & 7)) * 8]);
      }
      // S^T = K @ Q^T : C-layout col=qrow(lane&15), row=key(quad*4+r)
#pragma unroll
      for (int qt = 0; qt < 2; qt++) {
#pragma unroll
        for (int ntl = 0; ntl < 2; ntl++) {
          f32x4 s = {};
          s = __builtin_amdgcn_mfma_f32_16x16x32_bf16(ak[ntl][0], aq[qt][0], s, 0, 0, 0);
          s = __builtin_amdgcn_mfma_f32_16x16x32_bf16(ak[ntl][1], aq[qt][1], s, 0, 0, 0);
          bf16 p4[4];
#pragma unroll
          for (int r = 0; r < 4; r++) p4[r] = (bf16)__builtin_amdgcn_exp2f(s[r]);
          *(uint2*)(&Ps[wave][qt * 16 + lr][ntl * 16 + quad * 4]) = *(uint2*)p4;
        }
      }
      bf16x8 bvf[4];
#pragma unroll
      for (int ntv = 0; ntv < 4; ntv++) {
        const int vrow = ntv * 16 + lr;
        bvf[ntv] = *(const bf16x8*)(&Vsb[vrow * 128 + ((kc * 4 + quad) ^ lr) * 8]);
      }
      const bf16x8 mkfv = *(const bf16x8*)(mkb + kv0 + kc * 32 + quad * 8);
#pragma unroll
      for (int qt = 0; qt < 2; qt++) {
        bf16x8 ap = *(const bf16x8*)(&Ps[wave][qt * 16 + lr][quad * 8]);
#pragma unroll
        for (int ntv = 0; ntv < 4; ntv++)
          o_acc[qt][ntv] = __builtin_amdgcn_mfma_f32_16x16x32_bf16(ap, bvf[ntv], o_acc[qt][ntv], 0, 0, 0);
        l_acc[qt] = __builtin_amdgcn_mfma_f32_16x16x32_bf16(ap, mkfv, l_acc[qt], 0, 0, 0);
      }
    }
    buf ^= 1;
  }

#pragma unroll
  for (int qt = 0; qt < 2; qt++) {
#pragma unroll
    for (int ntv = 0; ntv < 4; ntv++) {
#pragma unroll
      for (int r = 0; r < 4; r++) {
        const int row = q0 + wave * 32 + qt * 16 + quad * 4 + r;
        O[(size_t)row * DMODEL + h * HDK + ntv * 16 + lr] =
            (bf16)(o_acc[qt][ntv][r] / l_acc[qt][r]);
      }
    }
  }
}

// ---------------- launch ----------------
extern "C" void kernel_launch(void* const* d_in, const int* in_sizes, int n_in,
                              void* d_out, int out_size, void* d_ws, size_t ws_size,
                              hipStream_t stream) {
  const float* x = (const float*)d_in[0];
  const int* mask = (const int*)d_in[1];
  const float* Wq = (const float*)d_in[2];
  const float* bq = (const float*)d_in[3];
  const float* Wk = (const float*)d_in[4];
  const float* bk = (const float*)d_in[5];
  const float* Wv = (const float*)d_in[6];
  const float* bv = (const float*)d_in[7];
  const float* Wo = (const float*)d_in[8];
  const float* bo = (const float*)d_in[9];
  float* out = (float*)d_out;

  char* w = (char*)d_ws;
  bf16* xb  = (bf16*)w; w += (size_t)S_LEN * DMODEL * 2;
  bf16* Wqt = (bf16*)w; w += (size_t)DMODEL * DMODEL * 2;  // packed B rows 0..1023
  bf16* Wkt = (bf16*)w; w += (size_t)DKV * DMODEL * 2;     // rows 1024..1279
  bf16* Wvt = (bf16*)w; w += (size_t)DKV * DMODEL * 2;     // rows 1280..1535
  bf16* Wot = (bf16*)w; w += (size_t)DMODEL * DMODEL * 2;
  bf16* Qb  = (bf16*)w; w += (size_t)S_LEN * DMODEL * 2;
  bf16* Kb  = (bf16*)w; w += (size_t)S_LEN * DKV * 2;
  bf16* Vtb = (bf16*)w; w += (size_t)DKV * S_LEN * 2;
  bf16* Ob  = (bf16*)w; w += (size_t)S_LEN * DMODEL * 2;
  float* mkf = (float*)w; w += (size_t)S_LEN * 4;
  bf16* mkb = (bf16*)w; w += (size_t)S_LEN * 2;

  // fused prep (1 dispatch): transposes + x convert + mask
  prep<<<dim3(32, 32, 6), 256, 0, stream>>>(
      x, mask, Wq, Wk, Wv, Wo, xb, mkf, mkb, Wqt, Wkt, Wvt, Wot);

  // fused QKV projection (packed N = 1536), XCD-scheduled 1D grid 768
  gemm_ld<1><<<dim3((S_LEN / 64) * (NTOT / 128)), 256, 0, stream>>>(
      xb, Wqt, S_LEN, NTOT, DMODEL, NTOT / 128, bq, bk, bv, mkf, Qb, Kb, Vtb,
      nullptr, nullptr);

  // attention
  flash_attn<<<dim3(S_LEN / 128, NHEADS), 256, 0, stream>>>(Qb, Kb, Vtb, mkb, Ob);

  // output projection (fp32 out), XCD-scheduled 1D grid 512
  gemm_ld<0><<<dim3((S_LEN / 64) * (DMODEL / 128)), 256, 0, stream>>>(
      Ob, Wot, S_LEN, DMODEL, DMODEL, DMODEL / 128, nullptr, nullptr, nullptr,
      nullptr, nullptr, nullptr, nullptr, bo, out);
}